// Round 3
// baseline (261.359 us; speedup 1.0000x reference)
//
#include <hip/hip_runtime.h>
#include <math.h>

#define CS 8
#define NBINS 8
#define IMG 224
#define HC 28                 // cells per side
#define OUTPER (HC*HC*NBINS)  // 6272
#define BATCH 256
#define P4 (IMG*IMG/4)        // 12544 float4 per plane
#define RS 32                 // pixel rows per hist block = 4 cell rows
#define GR (RS + 2)           // 34 gray rows staged (halo)
#define GSTRIDE 232           // floats per LDS row (16B-aligned float4 writes)
#define GOFF 4                // gray col c lives at g[row][c+GOFF]

// ---------------- kernel A: RGB -> gray (pure stream) + zero sumsq ---------
// grid: BATCH*P4/256 = 12544 blocks, one float4 per thread, loads batched.
__global__ __launch_bounds__(256) void hog_gray_kernel(
    const float4* __restrict__ x, float4* __restrict__ gray,
    float* __restrict__ sumsq)
{
    if (blockIdx.x == 0) sumsq[threadIdx.x] = 0.f;   // 256 threads cover BATCH
    int p = blockIdx.x * 256 + threadIdx.x;          // 0 .. BATCH*P4-1
    int b = p / P4;
    int i = p - b * P4;
    const float4* xb = x + (size_t)b * 3 * P4;
    float4 R = xb[i];
    float4 G = xb[P4 + i];
    float4 B = xb[2 * P4 + i];
    float4 g;
    g.x = 0.2989f * R.x + 0.587f * G.x + 0.114f * B.x;
    g.y = 0.2989f * R.y + 0.587f * G.y + 0.114f * B.y;
    g.z = 0.2989f * R.z + 0.587f * G.z + 0.114f * B.z;
    g.w = 0.2989f * R.w + 0.587f * G.w + 0.114f * B.w;
    gray[p] = g;
}

// ---------------- kernel B: per (image, 4-cell-row strip) histograms -------
// grid: (BATCH, 7), block 256. Register histograms + shfl_xor butterfly.
__global__ __launch_bounds__(256) void hog_hist_kernel(
    const float* __restrict__ gray, const float* __restrict__ gauss,
    float* __restrict__ out, float* __restrict__ sumsq)
{
    const int b   = blockIdx.x;
    const int by  = blockIdx.y;     // strip 0..6
    const int tid = threadIdx.x;
    const int r0  = by * RS;

    __shared__ float g[GR][GSTRIDE];
    __shared__ float wsum[4];

    // zero the left/right halo columns actually read (c=-1 and c=IMG)
    if (tid < GR * 2) {
        int rr = tid >> 1, cc = (tid & 1) ? (GOFF + IMG) : (GOFF - 1);
        g[rr][cc] = 0.f;
    }

    // stage gray rows r0-1 .. r0+32: clamped unconditional loads (batched),
    // zero-select after the load for out-of-image halo rows.
    const float4* gb = (const float4*)(gray + (size_t)b * IMG * IMG);
    #pragma unroll
    for (int k = 0; k < 8; ++k) {
        int idx = tid + k * 256;             // 0 .. 2047, need < 1904
        int ii  = idx < GR * 56 ? idx : GR * 56 - 1;
        int row = ii / 56, c4 = ii - row * 56;
        int gr  = r0 - 1 + row;
        int grc = gr < 0 ? 0 : (gr > IMG - 1 ? IMG - 1 : gr);
        float4 v = gb[grc * 56 + c4];
        if (gr < 0 || gr >= IMG) v = make_float4(0.f, 0.f, 0.f, 0.f);
        if (idx < GR * 56) *(float4*)&g[row][GOFF + c4 * 4] = v;
    }
    __syncthreads();

    float ssq = 0.f;
    if (tid < IMG) {
        const int c  = tid;
        const int wc = c & 7;

        float wgt[8];
        #pragma unroll
        for (int i = 0; i < 8; ++i) wgt[i] = gauss[i * 8 + wc];

        float h[8];
        #pragma unroll
        for (int k = 0; k < 8; ++k) h[k] = 0.f;

        auto dump = [&](int crow) {
            #pragma unroll
            for (int s = 1; s < 8; s <<= 1) {
                #pragma unroll
                for (int k = 0; k < 8; ++k) h[k] += __shfl_xor(h[k], s, 64);
            }
            float v = (wc < 4) ? ((wc < 2) ? (wc == 0 ? h[0] : h[1])
                                          : (wc == 2 ? h[2] : h[3]))
                               : ((wc < 6) ? (wc == 4 ? h[4] : h[5])
                                          : (wc == 6 ? h[6] : h[7]));
            out[(size_t)b * OUTPER + (size_t)crow * (HC * NBINS) + c] = v;
            ssq += v * v;
            #pragma unroll
            for (int k = 0; k < 8; ++k) h[k] = 0.f;
        };

        // 3x3 window in registers, rotate down the strip: 3 LDS reads/pixel
        float t0 = g[0][c + 3], t1 = g[0][c + 4], t2 = g[0][c + 5];
        float m0 = g[1][c + 3], m1 = g[1][c + 4], m2 = g[1][c + 5];

        #pragma unroll
        for (int sr = 0; sr < RS; ++sr) {
            float b0 = g[sr + 2][c + 3], b1 = g[sr + 2][c + 4], b2 = g[sr + 2][c + 5];
            float gx = (t2 - t0) + 2.f * (m2 - m0) + (b2 - b0);
            float gy = (b0 - t0) + 2.f * (b1 - t1) + (b2 - t2);
            float mag = sqrtf(gx * gx + gy * gy + 1e-6f);
            float ax = fabsf(gx), ay = fabsf(gy);

            // exact-octant bin == floor(mod(atan2(gy,gx),2pi)/(pi/4));
            // boundary semantics verified (R1/R2 passed, absmax ~2e-4)
            int bin;
            if (gy > 0.f)       bin = (gx > 0.f)  ? ((gy < gx) ? 0 : 1)
                                    : (gx == 0.f) ? 2 : ((ay > ax) ? 2 : 3);
            else if (gy == 0.f) bin = (gx < 0.f) ? 4 : 0;
            else                bin = (gx < 0.f)  ? ((ay < ax) ? 4 : 5)
                                    : (gx == 0.f) ? 6 : ((ay > ax) ? 6 : 7);

            float wm = wgt[sr & 7] * mag;
            #pragma unroll
            for (int k = 0; k < 8; ++k) h[k] += (bin == k) ? wm : 0.f;

            t0 = m0; t1 = m1; t2 = m2;
            m0 = b0; m1 = b1; m2 = b2;

            if ((sr & 7) == 7) dump(4 * by + (sr >> 3));
        }
    }

    // per-image sum of squares: wave reduce (inactive lanes contribute 0)
    #pragma unroll
    for (int o = 32; o > 0; o >>= 1) ssq += __shfl_down(ssq, o, 64);
    if ((tid & 63) == 0) wsum[tid >> 6] = ssq;
    __syncthreads();
    if (tid == 0) atomicAdd(&sumsq[b], wsum[0] + wsum[1] + wsum[2] + wsum[3]);
}

// ---------------- kernel C: in-place normalization -------------------------
__global__ __launch_bounds__(256) void hog_norm_kernel(
    float* __restrict__ out, const float* __restrict__ sumsq)
{
    int i = blockIdx.x * blockDim.x + threadIdx.x;   // float4 index
    const int vec_per_img = OUTPER / 4;              // 1568
    if (i >= BATCH * vec_per_img) return;
    int b = i / vec_per_img;
    float inv = 1.0f / (sqrtf(sumsq[b]) + 1e-6f);
    float4* o4 = (float4*)out;
    float4 v = o4[i];
    v.x *= inv; v.y *= inv; v.z *= inv; v.w *= inv;
    o4[i] = v;
}

extern "C" void kernel_launch(void* const* d_in, const int* in_sizes, int n_in,
                              void* d_out, int out_size, void* d_ws, size_t ws_size,
                              hipStream_t stream) {
    const float* x     = (const float*)d_in[0];
    const float* gauss = (const float*)d_in[1];
    // d_in[2]=kx, d_in[3]=ky: compile-time Sobel constants (hardcoded)
    float* out   = (float*)d_out;
    float* sumsq = (float*)d_ws;                 // 256 floats
    float* gray  = (float*)d_ws + 256;           // 51.4 MB, 16B-aligned

    hog_gray_kernel<<<BATCH * P4 / 256, 256, 0, stream>>>(
        (const float4*)x, (float4*)gray, sumsq);
    dim3 grid(BATCH, IMG / RS);                  // (256, 7)
    hog_hist_kernel<<<grid, 256, 0, stream>>>(gray, gauss, out, sumsq);
    hog_norm_kernel<<<(BATCH * OUTPER / 4 + 255) / 256, 256, 0, stream>>>(out, sumsq);
}

// Round 4
// 236.468 us; speedup vs baseline: 1.1053x; 1.1053x over previous
//
#include <hip/hip_runtime.h>
#include <math.h>

#define NBINS 8
#define IMG 224
#define HC 28                 // cells per side
#define OUTPER (HC*HC*NBINS)  // 6272
#define BATCH 256
#define PL4 12544             // float4 per 224x224 plane
#define GSTRIDE 232           // floats per LDS gray row (16B-aligned writes)
#define GOFF 4                // gray col c lives at g[slot][c+GOFF]
#define SLOTS 16              // rolling row buffer (pow2 >= 10 live rows)

// ---------------- fused kernel: gray + sobel + bin + cell hist -------------
// grid (BATCH, 4): block owns rows [by*56, by*56+55] = 7 strips of 8 rows
// (1 cell row each). Software pipeline: strip s+1's RGB loads are issued
// into registers before strip s's compute, so ~900-cycle HBM latency hides
// behind VALU work (fixes the R1-R3 convoy: stage/compute phases never
// overlapped, all pipes <25% busy).
__global__ __launch_bounds__(256) void hog_main_kernel(
    const float4* __restrict__ x, const float* __restrict__ gauss,
    float* __restrict__ out, float* __restrict__ partial)
{
    const int b     = blockIdx.x;
    const int by    = blockIdx.y;        // 0..3
    const int tid   = threadIdx.x;
    const int rbase = by * 56;

    __shared__ float g[SLOTS][GSTRIDE];
    __shared__ float wsum[4];

    const float4* xb = x + (size_t)b * 3 * PL4;

    // zero the left/right halo columns (c=-1, c=IMG) of every slot; staging
    // writes only touch words GOFF..GOFF+223, so these stay zero forever.
    if (tid < SLOTS * 2) {
        int rr = tid >> 1, cc = (tid & 1) ? (GOFF + IMG) : (GOFF - 1);
        g[rr][cc] = 0.f;
    }

    // ---- initial stage: rows rbase-1 .. rbase+8 (10 rows = 560 float4) ----
    {
        float4 R[3], G[3], B[3];
        int gr[3], c4[3]; bool act[3];
        #pragma unroll
        for (int k = 0; k < 3; ++k) {
            int idx = tid + k * 256;
            act[k] = idx < 560;
            int ii = act[k] ? idx : 0;
            int row = ii / 56; c4[k] = ii - row * 56;
            gr[k] = rbase - 1 + row;
            int grc = gr[k] < 0 ? 0 : (gr[k] > IMG - 1 ? IMG - 1 : gr[k]);
            const float4* p = xb + grc * 56 + c4[k];
            R[k] = p[0]; G[k] = p[PL4]; B[k] = p[2 * PL4];
        }
        #pragma unroll
        for (int k = 0; k < 3; ++k) if (act[k]) {
            bool z = (gr[k] < 0) || (gr[k] > IMG - 1);
            float4 v;
            v.x = z ? 0.f : 0.2989f * R[k].x + 0.587f * G[k].x + 0.114f * B[k].x;
            v.y = z ? 0.f : 0.2989f * R[k].y + 0.587f * G[k].y + 0.114f * B[k].y;
            v.z = z ? 0.f : 0.2989f * R[k].z + 0.587f * G[k].z + 0.114f * B[k].z;
            v.w = z ? 0.f : 0.2989f * R[k].w + 0.587f * G[k].w + 0.114f * B[k].w;
            *(float4*)&g[gr[k] & (SLOTS - 1)][GOFF + 4 * c4[k]] = v;
        }
    }
    __syncthreads();

    const int c = tid, wc = tid & 7;
    float wgt[8];
    #pragma unroll
    for (int i = 0; i < 8; ++i) wgt[i] = gauss[i * 8 + wc];
    float ssq = 0.f;

    for (int s = 0; s < 7; ++s) {
        // ---- issue prefetch of next strip's 8 rows (448 float4 units) ----
        float4 Rp[2], Gp[2], Bp[2];
        int pgr[2], pc4[2]; bool pact[2];
        if (s < 6) {
            #pragma unroll
            for (int k = 0; k < 2; ++k) {
                int idx = tid + k * 256;
                pact[k] = idx < 448;
                int ii = pact[k] ? idx : 0;
                int row = ii / 56; pc4[k] = ii - row * 56;
                pgr[k] = rbase + 8 * s + 9 + row;
                int grc = pgr[k] > IMG - 1 ? IMG - 1 : pgr[k];
                const float4* p = xb + grc * 56 + pc4[k];
                Rp[k] = p[0]; Gp[k] = p[PL4]; Bp[k] = p[2 * PL4];
            }
        }

        // ---- compute strip s (rows r0..r0+7 = cell row by*7+s) ----
        if (tid < IMG) {
            const int r0 = rbase + 8 * s;
            float h[8];
            #pragma unroll
            for (int k = 0; k < 8; ++k) h[k] = 0.f;

            int st = (r0 - 1) & (SLOTS - 1), sm = r0 & (SLOTS - 1);
            float t0 = g[st][c + 3], t1 = g[st][c + 4], t2 = g[st][c + 5];
            float m0 = g[sm][c + 3], m1 = g[sm][c + 4], m2 = g[sm][c + 5];

            #pragma unroll
            for (int sr = 0; sr < 8; ++sr) {
                int sb = (r0 + sr + 1) & (SLOTS - 1);
                float b0 = g[sb][c + 3], b1 = g[sb][c + 4], b2 = g[sb][c + 5];
                float gx = (t2 - t0) + 2.f * (m2 - m0) + (b2 - b0);
                float gy = (b0 - t0) + 2.f * (b1 - t1) + (b2 - t2);
                float mag = sqrtf(gx * gx + gy * gy + 1e-6f);
                float ax = fabsf(gx), ay = fabsf(gy);

                // exact-octant bin == floor(mod(atan2(gy,gx),2pi)/(pi/4));
                // boundary semantics verified (R1-R3 passed, absmax ~2e-4)
                int bin;
                if (gy > 0.f)       bin = (gx > 0.f)  ? ((gy < gx) ? 0 : 1)
                                        : (gx == 0.f) ? 2 : ((ay > ax) ? 2 : 3);
                else if (gy == 0.f) bin = (gx < 0.f) ? 4 : 0;
                else                bin = (gx < 0.f)  ? ((ay < ax) ? 4 : 5)
                                        : (gx == 0.f) ? 6 : ((ay > ax) ? 6 : 7);

                float wm = wgt[sr] * mag;
                #pragma unroll
                for (int k = 0; k < 8; ++k) h[k] += (bin == k) ? wm : 0.f;

                t0 = m0; t1 = m1; t2 = m2;
                m0 = b0; m1 = b1; m2 = b2;
            }

            // dump cell row: butterfly over the 8 lanes of each cell
            #pragma unroll
            for (int sh = 1; sh < 8; sh <<= 1) {
                #pragma unroll
                for (int k = 0; k < 8; ++k) h[k] += __shfl_xor(h[k], sh, 64);
            }
            float v = (wc < 4) ? ((wc < 2) ? (wc == 0 ? h[0] : h[1])
                                          : (wc == 2 ? h[2] : h[3]))
                               : ((wc < 6) ? (wc == 4 ? h[4] : h[5])
                                          : (wc == 6 ? h[6] : h[7]));
            int crow = by * 7 + s;
            out[(size_t)b * OUTPER + (size_t)crow * (HC * NBINS) + c] = v;
            ssq += v * v;
        }
        __syncthreads();   // all waves done reading old rows

        // ---- convert prefetched RGB -> gray, write into rolling buffer ----
        if (s < 6) {
            #pragma unroll
            for (int k = 0; k < 2; ++k) if (pact[k]) {
                bool z = pgr[k] > IMG - 1;
                float4 v;
                v.x = z ? 0.f : 0.2989f * Rp[k].x + 0.587f * Gp[k].x + 0.114f * Bp[k].x;
                v.y = z ? 0.f : 0.2989f * Rp[k].y + 0.587f * Gp[k].y + 0.114f * Bp[k].y;
                v.z = z ? 0.f : 0.2989f * Rp[k].z + 0.587f * Gp[k].z + 0.114f * Bp[k].z;
                v.w = z ? 0.f : 0.2989f * Rp[k].w + 0.587f * Gp[k].w + 0.114f * Bp[k].w;
                *(float4*)&g[pgr[k] & (SLOTS - 1)][GOFF + 4 * pc4[k]] = v;
            }
            __syncthreads();   // new rows visible before next compute
        }
    }

    // per-image sumsq partial (no atomics; every block writes its slot)
    #pragma unroll
    for (int o = 32; o > 0; o >>= 1) ssq += __shfl_down(ssq, o, 64);
    if ((tid & 63) == 0) wsum[tid >> 6] = ssq;
    __syncthreads();
    if (tid == 0) partial[by * BATCH + b] = wsum[0] + wsum[1] + wsum[2] + wsum[3];
}

// ---------------- normalization: divide by ||hist|| ------------------------
__global__ __launch_bounds__(256) void hog_norm_kernel(
    float* __restrict__ out, const float* __restrict__ partial)
{
    int i = blockIdx.x * blockDim.x + threadIdx.x;   // float4 index
    const int vec_per_img = OUTPER / 4;              // 1568
    if (i >= BATCH * vec_per_img) return;
    int b = i / vec_per_img;
    float s = partial[b] + partial[BATCH + b] + partial[2 * BATCH + b]
            + partial[3 * BATCH + b];
    float inv = 1.0f / (sqrtf(s) + 1e-6f);
    float4* o4 = (float4*)out;
    float4 v = o4[i];
    v.x *= inv; v.y *= inv; v.z *= inv; v.w *= inv;
    o4[i] = v;
}

extern "C" void kernel_launch(void* const* d_in, const int* in_sizes, int n_in,
                              void* d_out, int out_size, void* d_ws, size_t ws_size,
                              hipStream_t stream) {
    const float* x     = (const float*)d_in[0];
    const float* gauss = (const float*)d_in[1];
    // d_in[2]=kx, d_in[3]=ky: compile-time Sobel constants (hardcoded)
    float* out     = (float*)d_out;
    float* partial = (float*)d_ws;       // 4*BATCH floats, fully overwritten

    dim3 grid(BATCH, 4);
    hog_main_kernel<<<grid, 256, 0, stream>>>(
        (const float4*)x, gauss, out, partial);
    hog_norm_kernel<<<(BATCH * OUTPER / 4 + 255) / 256, 256, 0, stream>>>(out, partial);
}